// Round 4
// baseline (82.253 us; speedup 1.0000x reference)
//
#include <hip/hip_runtime.h>
#include <math.h>

// Problem constants (match reference)
#define BB 32
#define SS 52
#define AA 3
#define CC 80
// per-anchor pred row = C+5 = 85 floats; per-cell = 255 floats

constexpr int N_CELL = BB * SS * SS;        // 86528
constexpr int N_ANCH = N_CELL * AA;         // 259584 == 1014 * 256 exactly
constexpr int BLOCK  = 256;
constexpr int NBLK   = N_ANCH / BLOCK;      // 1014

// ws layout:
//   float partials[NBLK*6]  at byte 0      (24336 B)
//   uint  ticket            at byte 24576  (zeroed via hipMemsetAsync each call)

__global__ __launch_bounds__(BLOCK) void yolo_fused(
    const float* __restrict__ target,
    const float* __restrict__ pred,
    const float* __restrict__ anchors,
    float* __restrict__ ws,
    unsigned int* __restrict__ ticket,
    float* __restrict__ out)
{
    const int n    = blockIdx.x * BLOCK + threadIdx.x;  // exact grid, no bounds check
    const int lane = threadIdx.x & 63;
    const int grp  = lane >> 4;        // quarter-wave group 0..3
    const int l16  = lane & 15;

    const int cell = n / 3;
    const int a    = n - cell * 3;
    const float* t = target + (size_t)n * 6;
    const int poff = cell * 255 + a * 85;

    // target row is 24B, 8B-aligned -> float2 loads
    const float2 t01 = *reinterpret_cast<const float2*>(t);
    const float y = t01.x;
    const float l = pred[poff];        // objectness logit (gather)

    float s_obj = 0.f, s_noobj = 0.f, s_bce = 0.f, s_ce = 0.f, s_sq = 0.f, s_objt = 0.f;
    int label_l = 0;
    const bool isobj = (y != 0.0f);

    if (!isobj) {
        s_noobj = 1.0f;
        s_bce   = fmaxf(l, 0.0f) + log1pf(expf(-fabsf(l)));
    } else {
        s_obj = 1.0f;
        const float2 t23 = *reinterpret_cast<const float2*>(t + 2);
        const float2 t45 = *reinterpret_cast<const float2*>(t + 4);
        label_l = (int)t45.y;

        // ---- box MSE in transformed space ----
        float aw = anchors[a * 2 + 0];
        float ah = anchors[a * 2 + 1];
        float px = 1.0f / (1.0f + expf(-pred[poff + 1]));
        float py = 1.0f / (1.0f + expf(-pred[poff + 2]));
        float pw = pred[poff + 3];
        float ph = pred[poff + 4];
        float tx = t01.y, ty = t23.x;
        float tw = logf(1e-16f + t23.y / aw);
        float th = logf(1e-16f + t45.x / ah);
        float dx = tx - px, dy = ty - py, dw = tw - pw, dh = th - ph;
        s_sq = dx * dx + dy * dy + dw * dw + dh * dh;

        // ---- objectness MSE vs IoU (faithful reference quirk) ----
        float bw = expf(pw) * aw;
        float bh = expf(ph) * ah;
        float b1x1 = px - bw * 0.5f, b1x2 = px + bw * 0.5f;
        float b1y1 = py - bh * 0.5f, b1y2 = py + bh * 0.5f;
        float b2x1 = tx - tw * 0.5f, b2x2 = tx + tw * 0.5f;
        float b2y1 = ty - th * 0.5f, b2y2 = ty + th * 0.5f;
        float iw = fmaxf(fminf(b1x2, b2x2) - fmaxf(b1x1, b2x1), 0.0f);
        float ih = fmaxf(fminf(b1y2, b2y2) - fmaxf(b1y1, b2y1), 0.0f);
        float inter = iw * ih;
        float a1 = fabsf((b1x2 - b1x1) * (b1y2 - b1y1));
        float a2 = fabsf((b2x2 - b2x1) * (b2y2 - b2y1));
        float iou = inter / (a1 + a2 - inter + 1e-6f);
        float d = iou - l;
        s_objt = d * d;
    }

    // ---- cooperative class CE: 4 obj anchors per iteration, 16 lanes each ----
    unsigned long long m = __ballot(isobj);
    while (m) {
        int b0 = -1, b1 = -1, b2 = -1, b3 = -1;
        if (m) { b0 = __ffsll(m) - 1; m &= m - 1; }
        if (m) { b1 = __ffsll(m) - 1; m &= m - 1; }
        if (m) { b2 = __ffsll(m) - 1; m &= m - 1; }
        if (m) { b3 = __ffsll(m) - 1; m &= m - 1; }
        int src = (grp == 0) ? b0 : (grp == 1) ? b1 : (grp == 2) ? b2 : b3;
        bool active = (src >= 0);
        int s = active ? src : 0;
        int offu  = __shfl(poff, s, 64) + 5;
        int label = __shfl(label_l, s, 64);
        const float* cl = pred + offu + l16 * 5;

        float v0 = 0.f, v1 = 0.f, v2 = 0.f, v3 = 0.f, v4 = 0.f;
        if (active) { v0 = cl[0]; v1 = cl[1]; v2 = cl[2]; v3 = cl[3]; v4 = cl[4]; }

        float mx = fmaxf(fmaxf(fmaxf(v0, v1), fmaxf(v2, v3)), v4);
        #pragma unroll
        for (int o = 8; o > 0; o >>= 1) mx = fmaxf(mx, __shfl_xor(mx, o, 16));

        float se = expf(v0 - mx) + expf(v1 - mx) + expf(v2 - mx)
                 + expf(v3 - mx) + expf(v4 - mx);
        #pragma unroll
        for (int o = 8; o > 0; o >>= 1) se += __shfl_xor(se, o, 16);

        int e = label % 5;   // element within owner lane
        float cand = (e == 0) ? v0 : (e == 1) ? v1 : (e == 2) ? v2 : (e == 3) ? v3 : v4;
        float cll  = __shfl(cand, (grp << 4) + label / 5, 64);

        if (active && l16 == 0) s_ce += (mx + logf(se)) - cll;
    }

    // ---- wave-64 tree reduction ----
    #pragma unroll
    for (int off = 32; off > 0; off >>= 1) {
        s_obj   += __shfl_down(s_obj,   off, 64);
        s_noobj += __shfl_down(s_noobj, off, 64);
        s_bce   += __shfl_down(s_bce,   off, 64);
        s_ce    += __shfl_down(s_ce,    off, 64);
        s_sq    += __shfl_down(s_sq,    off, 64);
        s_objt  += __shfl_down(s_objt,  off, 64);
    }

    // ---- block reduction through LDS, write per-block partials ----
    __shared__ float red[4][6];
    __shared__ unsigned int s_last;
    int wave = threadIdx.x >> 6;
    if ((threadIdx.x & 63) == 0) {
        red[wave][0] = s_obj;  red[wave][1] = s_noobj; red[wave][2] = s_bce;
        red[wave][3] = s_ce;   red[wave][4] = s_sq;    red[wave][5] = s_objt;
    }
    __syncthreads();
    if (threadIdx.x < 6) {
        float v = red[0][threadIdx.x] + red[1][threadIdx.x]
                + red[2][threadIdx.x] + red[3][threadIdx.x];
        ws[(size_t)blockIdx.x * 6 + threadIdx.x] = v;
    }

    // ---- last-block-done finalize (rocPRIM pattern) ----
    __threadfence();                       // release partial stores (device scope)
    __syncthreads();
    if (threadIdx.x == 0) {
        unsigned int old = atomicAdd(ticket, 1u);
        s_last = (old == (unsigned int)(NBLK - 1)) ? 1u : 0u;
    }
    __syncthreads();
    if (s_last) {
        __threadfence();                   // acquire: see all blocks' partials
        float acc[6] = {0.f, 0.f, 0.f, 0.f, 0.f, 0.f};
        for (int b = threadIdx.x; b < NBLK; b += BLOCK) {
            const float* p = ws + (size_t)b * 6;  // 24B rows, 8B-aligned
            float2 p01 = *reinterpret_cast<const float2*>(p);
            float2 p23 = *reinterpret_cast<const float2*>(p + 2);
            float2 p45 = *reinterpret_cast<const float2*>(p + 4);
            acc[0] += p01.x; acc[1] += p01.y; acc[2] += p23.x;
            acc[3] += p23.y; acc[4] += p45.x; acc[5] += p45.y;
        }
        #pragma unroll
        for (int off = 32; off > 0; off >>= 1) {
            #pragma unroll
            for (int k = 0; k < 6; ++k) acc[k] += __shfl_down(acc[k], off, 64);
        }
        __shared__ float red2[4][6];
        if ((threadIdx.x & 63) == 0) {
            #pragma unroll
            for (int k = 0; k < 6; ++k) red2[wave][k] = acc[k];
        }
        __syncthreads();
        if (threadIdx.x == 0) {
            float tt[6];
            #pragma unroll
            for (int k = 0; k < 6; ++k)
                tt[k] = red2[0][k] + red2[1][k] + red2[2][k] + red2[3][k];
            float n_obj   = fmaxf(tt[0], 1.0f);
            float n_noobj = fmaxf(tt[1], 1.0f);
            float noobjloss = tt[2] / n_noobj;
            float classloss = tt[3] / n_obj;
            float boxloss   = tt[4] / (4.0f * n_obj);
            float objloss   = tt[5] / n_obj;
            out[0] = 10.0f * noobjloss + 1.0f * classloss
                   + 10.0f * boxloss + 1.0f * objloss;
        }
    }
}

extern "C" void kernel_launch(void* const* d_in, const int* in_sizes, int n_in,
                              void* d_out, int out_size, void* d_ws, size_t ws_size,
                              hipStream_t stream) {
    const float* target  = (const float*)d_in[0];
    const float* pred    = (const float*)d_in[1];
    const float* anchors = (const float*)d_in[2];
    float* out = (float*)d_out;
    float* ws  = (float*)d_ws;
    unsigned int* ticket = (unsigned int*)((char*)d_ws + 24576);

    // zero the ticket counter each call (graph-capture legal, deterministic)
    hipMemsetAsync(ticket, 0, sizeof(unsigned int), stream);

    hipLaunchKernelGGL(yolo_fused, dim3(NBLK), dim3(BLOCK), 0, stream,
                       target, pred, anchors, ws, ticket, out);
}

// Round 5
// 22.264 us; speedup vs baseline: 3.6945x; 3.6945x over previous
//
#include <hip/hip_runtime.h>
#include <math.h>

// Problem constants (match reference)
#define BB 32
#define SS 52
#define AA 3
#define CC 80
// per-anchor pred row = C+5 = 85 floats; per-cell = 255 floats

constexpr int N_CELL = BB * SS * SS;        // 86528
constexpr int N_ANCH = N_CELL * AA;         // 259584
constexpr int BLOCK  = 256;
constexpr int SLOTS  = 3;                   // anchors per thread
constexpr int NBLKM  = N_ANCH / (BLOCK * SLOTS);  // 338 exactly
constexpr int STRIDE = NBLKM * BLOCK;             // 86528

// ws layout (floats): per-block partials, 6 per block: NBLKM*6 = 2028 floats
// [blk*6+0] sum obj_f   [1] sum noobj_f  [2] sum bce*noobj
// [3] sum ce*obj        [4] sum sq*obj   [5] sum objterm*obj

__global__ __launch_bounds__(BLOCK) void yolo_main(
    const float* __restrict__ target,
    const float* __restrict__ pred,
    const float* __restrict__ anchors,
    float* __restrict__ ws)
{
    const int tid  = threadIdx.x;
    const int base = blockIdx.x * BLOCK + tid;   // < STRIDE always
    const int lane = tid & 63;
    const int grp  = lane >> 4;                  // quarter-wave group 0..3
    const int l16  = lane & 15;

    // ---- issue all independent loads up-front (MLP = 6 per thread) ----
    float2 t01[SLOTS];
    float  lg[SLOTS];
    int    poff[SLOTS], aidx[SLOTS];
    #pragma unroll
    for (int k = 0; k < SLOTS; ++k) {
        int n    = base + k * STRIDE;
        int cell = n / 3;
        int a    = n - cell * 3;
        aidx[k] = a;
        poff[k] = cell * 255 + a * 85;
        t01[k]  = *reinterpret_cast<const float2*>(target + (size_t)n * 6);
    }
    #pragma unroll
    for (int k = 0; k < SLOTS; ++k) lg[k] = pred[poff[k]];

    float s_obj = 0.f, s_noobj = 0.f, s_bce = 0.f, s_ce = 0.f, s_sq = 0.f, s_objt = 0.f;

    #pragma unroll
    for (int k = 0; k < SLOTS; ++k) {
        const int n = base + k * STRIDE;
        const float y = t01[k].x;
        const float l = lg[k];
        const bool isobj = (y != 0.0f);
        int label_l = 0;

        if (!isobj) {
            s_noobj += 1.0f;
            s_bce   += fmaxf(l, 0.0f) + log1pf(expf(-fabsf(l)));
        } else {
            s_obj += 1.0f;
            const float* t = target + (size_t)n * 6;
            const float2 t23 = *reinterpret_cast<const float2*>(t + 2);
            const float2 t45 = *reinterpret_cast<const float2*>(t + 4);
            label_l = (int)t45.y;
            const int po = poff[k];
            const int a  = aidx[k];

            // ---- box MSE in transformed space ----
            float aw = anchors[a * 2 + 0];
            float ah = anchors[a * 2 + 1];
            float px = 1.0f / (1.0f + expf(-pred[po + 1]));
            float py = 1.0f / (1.0f + expf(-pred[po + 2]));
            float pw = pred[po + 3];
            float ph = pred[po + 4];
            float tx = t01[k].y, ty = t23.x;
            float tw = logf(1e-16f + t23.y / aw);
            float th = logf(1e-16f + t45.x / ah);
            float dx = tx - px, dy = ty - py, dw = tw - pw, dh = th - ph;
            s_sq += dx * dx + dy * dy + dw * dw + dh * dh;

            // ---- objectness MSE vs IoU (faithful reference quirk:
            // decoded pred box vs log-space target box) ----
            float bw = expf(pw) * aw;
            float bh = expf(ph) * ah;
            float b1x1 = px - bw * 0.5f, b1x2 = px + bw * 0.5f;
            float b1y1 = py - bh * 0.5f, b1y2 = py + bh * 0.5f;
            float b2x1 = tx - tw * 0.5f, b2x2 = tx + tw * 0.5f;
            float b2y1 = ty - th * 0.5f, b2y2 = ty + th * 0.5f;
            float iw = fmaxf(fminf(b1x2, b2x2) - fmaxf(b1x1, b2x1), 0.0f);
            float ih = fmaxf(fminf(b1y2, b2y2) - fmaxf(b1y1, b2y1), 0.0f);
            float inter = iw * ih;
            float a1 = fabsf((b1x2 - b1x1) * (b1y2 - b1y1));
            float a2 = fabsf((b2x2 - b2x1) * (b2y2 - b2y1));
            float iou = inter / (a1 + a2 - inter + 1e-6f);
            float d = iou - l;
            s_objt += d * d;
        }

        // ---- cooperative class CE: 4 obj anchors per iter, 16 lanes each ----
        unsigned long long m = __ballot(isobj);
        while (m) {
            int b0 = -1, b1 = -1, b2 = -1, b3 = -1;
            if (m) { b0 = __ffsll(m) - 1; m &= m - 1; }
            if (m) { b1 = __ffsll(m) - 1; m &= m - 1; }
            if (m) { b2 = __ffsll(m) - 1; m &= m - 1; }
            if (m) { b3 = __ffsll(m) - 1; m &= m - 1; }
            int src = (grp == 0) ? b0 : (grp == 1) ? b1 : (grp == 2) ? b2 : b3;
            bool active = (src >= 0);
            int s = active ? src : 0;
            int offu  = __shfl(poff[k], s, 64) + 5;
            int label = __shfl(label_l, s, 64);
            const float* cl = pred + offu + l16 * 5;

            float v0 = 0.f, v1 = 0.f, v2 = 0.f, v3 = 0.f, v4 = 0.f;
            if (active) { v0 = cl[0]; v1 = cl[1]; v2 = cl[2]; v3 = cl[3]; v4 = cl[4]; }

            float mx = fmaxf(fmaxf(fmaxf(v0, v1), fmaxf(v2, v3)), v4);
            #pragma unroll
            for (int o = 8; o > 0; o >>= 1) mx = fmaxf(mx, __shfl_xor(mx, o, 16));

            float se = expf(v0 - mx) + expf(v1 - mx) + expf(v2 - mx)
                     + expf(v3 - mx) + expf(v4 - mx);
            #pragma unroll
            for (int o = 8; o > 0; o >>= 1) se += __shfl_xor(se, o, 16);

            int e = label % 5;
            float cand = (e == 0) ? v0 : (e == 1) ? v1 : (e == 2) ? v2
                       : (e == 3) ? v3 : v4;
            float cll  = __shfl(cand, (grp << 4) + label / 5, 64);

            if (active && l16 == 0) s_ce += (mx + logf(se)) - cll;
        }
    }

    // ---- wave-64 tree reduction ----
    #pragma unroll
    for (int off = 32; off > 0; off >>= 1) {
        s_obj   += __shfl_down(s_obj,   off, 64);
        s_noobj += __shfl_down(s_noobj, off, 64);
        s_bce   += __shfl_down(s_bce,   off, 64);
        s_ce    += __shfl_down(s_ce,    off, 64);
        s_sq    += __shfl_down(s_sq,    off, 64);
        s_objt  += __shfl_down(s_objt,  off, 64);
    }

    // ---- block reduction through LDS, write per-block partials ----
    __shared__ float red[4][6];
    int wave = tid >> 6;
    if ((tid & 63) == 0) {
        red[wave][0] = s_obj;  red[wave][1] = s_noobj; red[wave][2] = s_bce;
        red[wave][3] = s_ce;   red[wave][4] = s_sq;    red[wave][5] = s_objt;
    }
    __syncthreads();
    if (tid < 6) {
        float v = red[0][tid] + red[1][tid] + red[2][tid] + red[3][tid];
        ws[(size_t)blockIdx.x * 6 + tid] = v;
    }
}

__global__ __launch_bounds__(256) void yolo_final(const float* __restrict__ ws,
                                                  float* __restrict__ out) {
    float acc[6] = {0.f, 0.f, 0.f, 0.f, 0.f, 0.f};
    for (int b = threadIdx.x; b < NBLKM; b += 256) {
        const float* p = ws + (size_t)b * 6;     // 24B rows, 8B-aligned
        float2 p01 = *reinterpret_cast<const float2*>(p);
        float2 p23 = *reinterpret_cast<const float2*>(p + 2);
        float2 p45 = *reinterpret_cast<const float2*>(p + 4);
        acc[0] += p01.x; acc[1] += p01.y; acc[2] += p23.x;
        acc[3] += p23.y; acc[4] += p45.x; acc[5] += p45.y;
    }
    #pragma unroll
    for (int off = 32; off > 0; off >>= 1) {
        #pragma unroll
        for (int k = 0; k < 6; ++k) acc[k] += __shfl_down(acc[k], off, 64);
    }
    __shared__ float red[4][6];
    int wave = threadIdx.x >> 6;
    if ((threadIdx.x & 63) == 0) {
        #pragma unroll
        for (int k = 0; k < 6; ++k) red[wave][k] = acc[k];
    }
    __syncthreads();
    if (threadIdx.x == 0) {
        float t[6];
        #pragma unroll
        for (int k = 0; k < 6; ++k)
            t[k] = red[0][k] + red[1][k] + red[2][k] + red[3][k];
        float n_obj   = fmaxf(t[0], 1.0f);
        float n_noobj = fmaxf(t[1], 1.0f);
        float noobjloss = t[2] / n_noobj;
        float classloss = t[3] / n_obj;
        float boxloss   = t[4] / (4.0f * n_obj);
        float objloss   = t[5] / n_obj;
        // L_NOOBJ*noobj + L_CLASS*class + L_BOX*box + L_OBJ*obj
        out[0] = 10.0f * noobjloss + 1.0f * classloss + 10.0f * boxloss + 1.0f * objloss;
    }
}

extern "C" void kernel_launch(void* const* d_in, const int* in_sizes, int n_in,
                              void* d_out, int out_size, void* d_ws, size_t ws_size,
                              hipStream_t stream) {
    const float* target  = (const float*)d_in[0];
    const float* pred    = (const float*)d_in[1];
    const float* anchors = (const float*)d_in[2];
    float* out = (float*)d_out;
    float* ws  = (float*)d_ws;

    hipLaunchKernelGGL(yolo_main, dim3(NBLKM), dim3(BLOCK), 0, stream,
                       target, pred, anchors, ws);

    hipLaunchKernelGGL(yolo_final, dim3(1), dim3(256), 0, stream, ws, out);
}

// Round 6
// 17.434 us; speedup vs baseline: 4.7181x; 1.2770x over previous
//
#include <hip/hip_runtime.h>
#include <math.h>

// Problem constants (match reference)
#define BB 32
#define SS 52
#define AA 3
#define CC 80
// per-anchor pred row = C+5 = 85 floats; per-cell = 255 floats

constexpr int N_CELL = BB * SS * SS;        // 86528
constexpr int N_ANCH = N_CELL * AA;         // 259584 == 1014 * 256 exactly
constexpr int BLOCK  = 256;
constexpr int NBLK   = N_ANCH / BLOCK;      // 1014

__device__ __forceinline__ float fast_rcp(float x) {
    return __builtin_amdgcn_rcpf(x);
}

// ws layout (floats): per-block partials, 6 per block (NBLK*6 = 6084 floats)
// [blk*6+0] sum obj_f   [1] sum noobj_f  [2] sum bce*noobj
// [3] sum ce*obj        [4] sum sq*obj   [5] sum objterm*obj

__global__ __launch_bounds__(BLOCK) void yolo_main(
    const float* __restrict__ target,
    const float* __restrict__ pred,
    const float* __restrict__ anchors,
    float* __restrict__ ws)
{
    const int tid  = threadIdx.x;
    const int n    = blockIdx.x * BLOCK + tid;   // exact grid, no bounds check
    const int lane = tid & 63;
    const int grp  = lane >> 4;                  // quarter-wave group 0..3
    const int l16  = lane & 15;

    const int cell = n / 3;
    const int a    = n - cell * 3;
    const float* t = target + (size_t)n * 6;
    const int poff = cell * 255 + a * 85;

    // ---- phase 0: cheap loads ----
    const float2 t01 = *reinterpret_cast<const float2*>(t);
    const float  l   = pred[poff];               // objectness logit (gather)
    const bool isobj = (t01.x != 0.0f);

    // ---- phase 1: prefetch ALL obj-path operands before any math,
    //      so the masked gathers are all in flight concurrently ----
    float2 t23, t45;
    float p1, p2, p3, p4, aw, ah;
    if (isobj) {
        t23 = *reinterpret_cast<const float2*>(t + 2);
        t45 = *reinterpret_cast<const float2*>(t + 4);
        p1 = pred[poff + 1];
        p2 = pred[poff + 2];
        p3 = pred[poff + 3];
        p4 = pred[poff + 4];
        aw = anchors[a * 2 + 0];
        ah = anchors[a * 2 + 1];
    }

    float s_obj = 0.f, s_noobj = 0.f, s_bce = 0.f, s_ce = 0.f, s_sq = 0.f, s_objt = 0.f;
    int label_l = 0;

    // ---- phase 2: math (native transcendentals; abs tolerance is 0.49) ----
    if (!isobj) {
        // softplus(-|l|) = log(1 + e^-|l|), argument in (1,2] -> native log safe
        s_noobj = 1.0f;
        s_bce   = fmaxf(l, 0.0f) + __logf(1.0f + __expf(-fabsf(l)));
    } else {
        s_obj   = 1.0f;
        label_l = (int)t45.y;

        // box MSE in transformed space
        float px = fast_rcp(1.0f + __expf(-p1));   // sigmoid
        float py = fast_rcp(1.0f + __expf(-p2));
        float tx = t01.y, ty = t23.x;
        float tw = __logf(1e-16f + t23.y * fast_rcp(aw));
        float th = __logf(1e-16f + t45.x * fast_rcp(ah));
        float dx = tx - px, dy = ty - py, dw = tw - p3, dh = th - p4;
        s_sq = dx * dx + dy * dy + dw * dw + dh * dh;

        // objectness MSE vs IoU (faithful reference quirk:
        // decoded pred box vs log-space target box)
        float bw = __expf(p3) * aw;
        float bh = __expf(p4) * ah;
        float b1x1 = px - bw * 0.5f, b1x2 = px + bw * 0.5f;
        float b1y1 = py - bh * 0.5f, b1y2 = py + bh * 0.5f;
        float b2x1 = tx - tw * 0.5f, b2x2 = tx + tw * 0.5f;
        float b2y1 = ty - th * 0.5f, b2y2 = ty + th * 0.5f;
        float iw = fmaxf(fminf(b1x2, b2x2) - fmaxf(b1x1, b2x1), 0.0f);
        float ih = fmaxf(fminf(b1y2, b2y2) - fmaxf(b1y1, b2y1), 0.0f);
        float inter = iw * ih;
        float a1 = fabsf((b1x2 - b1x1) * (b1y2 - b1y1));
        float a2 = fabsf((b2x2 - b2x1) * (b2y2 - b2y1));
        float iou = inter * fast_rcp(a1 + a2 - inter + 1e-6f);
        float d = iou - l;
        s_objt = d * d;
    }

    // ---- phase 3: cooperative class CE, 4 obj anchors per iter, 16 lanes each ----
    unsigned long long m = __ballot(isobj);
    while (m) {
        int b0 = -1, b1 = -1, b2 = -1, b3 = -1;
        if (m) { b0 = __ffsll(m) - 1; m &= m - 1; }
        if (m) { b1 = __ffsll(m) - 1; m &= m - 1; }
        if (m) { b2 = __ffsll(m) - 1; m &= m - 1; }
        if (m) { b3 = __ffsll(m) - 1; m &= m - 1; }
        int src = (grp == 0) ? b0 : (grp == 1) ? b1 : (grp == 2) ? b2 : b3;
        bool active = (src >= 0);
        int s = active ? src : 0;
        int offu  = __shfl(poff, s, 64) + 5;
        int label = __shfl(label_l, s, 64);
        const float* cl = pred + offu + l16 * 5;

        float v0 = 0.f, v1 = 0.f, v2 = 0.f, v3 = 0.f, v4 = 0.f;
        if (active) { v0 = cl[0]; v1 = cl[1]; v2 = cl[2]; v3 = cl[3]; v4 = cl[4]; }

        float mx = fmaxf(fmaxf(fmaxf(v0, v1), fmaxf(v2, v3)), v4);
        #pragma unroll
        for (int o = 8; o > 0; o >>= 1) mx = fmaxf(mx, __shfl_xor(mx, o, 16));

        float se = __expf(v0 - mx) + __expf(v1 - mx) + __expf(v2 - mx)
                 + __expf(v3 - mx) + __expf(v4 - mx);
        #pragma unroll
        for (int o = 8; o > 0; o >>= 1) se += __shfl_xor(se, o, 16);

        int e = label % 5;
        float cand = (e == 0) ? v0 : (e == 1) ? v1 : (e == 2) ? v2
                   : (e == 3) ? v3 : v4;
        float cll  = __shfl(cand, (grp << 4) + label / 5, 64);

        if (active && l16 == 0) s_ce += (mx + __logf(se)) - cll;
    }

    // ---- wave-64 tree reduction ----
    #pragma unroll
    for (int off = 32; off > 0; off >>= 1) {
        s_obj   += __shfl_down(s_obj,   off, 64);
        s_noobj += __shfl_down(s_noobj, off, 64);
        s_bce   += __shfl_down(s_bce,   off, 64);
        s_ce    += __shfl_down(s_ce,    off, 64);
        s_sq    += __shfl_down(s_sq,    off, 64);
        s_objt  += __shfl_down(s_objt,  off, 64);
    }

    // ---- block reduction through LDS, write per-block partials ----
    __shared__ float red[4][6];
    int wave = tid >> 6;
    if ((tid & 63) == 0) {
        red[wave][0] = s_obj;  red[wave][1] = s_noobj; red[wave][2] = s_bce;
        red[wave][3] = s_ce;   red[wave][4] = s_sq;    red[wave][5] = s_objt;
    }
    __syncthreads();
    if (tid < 6) {
        float v = red[0][tid] + red[1][tid] + red[2][tid] + red[3][tid];
        ws[(size_t)blockIdx.x * 6 + tid] = v;
    }
}

__global__ __launch_bounds__(256) void yolo_final(const float* __restrict__ ws,
                                                  float* __restrict__ out) {
    float acc[6] = {0.f, 0.f, 0.f, 0.f, 0.f, 0.f};
    for (int b = threadIdx.x; b < NBLK; b += 256) {
        const float* p = ws + (size_t)b * 6;     // 24B rows, 8B-aligned
        float2 p01 = *reinterpret_cast<const float2*>(p);
        float2 p23 = *reinterpret_cast<const float2*>(p + 2);
        float2 p45 = *reinterpret_cast<const float2*>(p + 4);
        acc[0] += p01.x; acc[1] += p01.y; acc[2] += p23.x;
        acc[3] += p23.y; acc[4] += p45.x; acc[5] += p45.y;
    }
    #pragma unroll
    for (int off = 32; off > 0; off >>= 1) {
        #pragma unroll
        for (int k = 0; k < 6; ++k) acc[k] += __shfl_down(acc[k], off, 64);
    }
    __shared__ float red[4][6];
    int wave = threadIdx.x >> 6;
    if ((threadIdx.x & 63) == 0) {
        #pragma unroll
        for (int k = 0; k < 6; ++k) red[wave][k] = acc[k];
    }
    __syncthreads();
    if (threadIdx.x == 0) {
        float t[6];
        #pragma unroll
        for (int k = 0; k < 6; ++k)
            t[k] = red[0][k] + red[1][k] + red[2][k] + red[3][k];
        float n_obj   = fmaxf(t[0], 1.0f);
        float n_noobj = fmaxf(t[1], 1.0f);
        float noobjloss = t[2] / n_noobj;
        float classloss = t[3] / n_obj;
        float boxloss   = t[4] / (4.0f * n_obj);
        float objloss   = t[5] / n_obj;
        // L_NOOBJ*noobj + L_CLASS*class + L_BOX*box + L_OBJ*obj
        out[0] = 10.0f * noobjloss + 1.0f * classloss + 10.0f * boxloss + 1.0f * objloss;
    }
}

extern "C" void kernel_launch(void* const* d_in, const int* in_sizes, int n_in,
                              void* d_out, int out_size, void* d_ws, size_t ws_size,
                              hipStream_t stream) {
    const float* target  = (const float*)d_in[0];
    const float* pred    = (const float*)d_in[1];
    const float* anchors = (const float*)d_in[2];
    float* out = (float*)d_out;
    float* ws  = (float*)d_ws;

    hipLaunchKernelGGL(yolo_main, dim3(NBLK), dim3(BLOCK), 0, stream,
                       target, pred, anchors, ws);

    hipLaunchKernelGGL(yolo_final, dim3(1), dim3(256), 0, stream, ws, out);
}